// Round 10
// baseline (1203.176 us; speedup 1.0000x reference)
//
#include <hip/hip_runtime.h>
#include <hip/hip_bf16.h>
#include <hip/hip_fp8.h>
#include <math.h>

typedef __hip_bfloat16 bf16;
typedef __attribute__((ext_vector_type(8))) short short8;
typedef __attribute__((ext_vector_type(4))) float f32x4;

#define NPB   65536   // positions per batch (16*64*64)
#define DIMC  48
#define C2    192
#define HIDC  96
#define TT    16

static __device__ __forceinline__ float b2f(bf16 v) { return __bfloat162float(v); }
static __device__ __forceinline__ bf16  f2b(float v) { return __float2bfloat16(v); }
static __device__ __forceinline__ unsigned short f2us(float v) {
  return __bfloat16_as_ushort(__float2bfloat16(v));
}
static __device__ __forceinline__ unsigned char f2fp8(float v) {
  __hip_fp8_e4m3 t(v); return (unsigned char)t.__x;
}
static __device__ __forceinline__ float fp82f(unsigned char u) {
  __hip_fp8_e4m3 t; t.__x = (__hip_fp8_storage_t)u; return (float)t;
}

// ---------------- y = LN(x) over 48 channels, bf16 out (LN1 and LN2) -------------
__global__ __launch_bounds__(256) void k_ln(
    const float* __restrict__ x, const float* __restrict__ lw, const float* __restrict__ lb,
    bf16* __restrict__ y) {
  int p = blockIdx.x * 256 + threadIdx.x;   // 0..131071
  int b = p >> 16, n = p & (NPB - 1);
  const float* xb = x + ((size_t)b * DIMC) * NPB + n;
  float v[DIMC]; float s = 0.f, s2 = 0.f;
#pragma unroll
  for (int c = 0; c < DIMC; ++c) { float t = xb[(size_t)c * NPB]; v[c] = t; s += t; s2 += t * t; }
  float mu = s * (1.f / DIMC);
  float var = fmaxf(s2 * (1.f / DIMC) - mu * mu, 0.f);
  float rs = rsqrtf(var + 1e-5f);
  bf16* yb = y + ((size_t)b * DIMC) * NPB + n;
#pragma unroll
  for (int c = 0; c < DIMC; ++c) yb[(size_t)c * NPB] = f2b((v[c] - mu) * rs * lw[c] + lb[c]);
}

// ------- MFMA 1x1 conv, sectioned, fp8(x16) out. grid (NSEC, 1024) ----------------
// hp >= 0: qkv head-pair mapping (sec 0..5 -> q(2hp),q(2hp+1),k0,k1,v0,v1)
// hp <  0: plain rows sec*48 (FFN pin).
__global__ __launch_bounds__(256) void k_pconv_sec(
    const bf16* __restrict__ y, const float* __restrict__ W,
    const float* __restrict__ bias, int hp, unsigned char* __restrict__ dst, int dcs) {
  __shared__ unsigned short Yl[64][130];
  __shared__ unsigned short Wl[48][72];
  int tid = threadIdx.x;
  int sec = blockIdx.x;
  int row = (hp >= 0) ? ((sec >> 1) * 192 + (2 * hp + (sec & 1)) * 48) : sec * 48;
  int bt = blockIdx.y;
  int b = bt >> 9;
  int n0 = (bt & 511) * 128;
  const unsigned short* yb = (const unsigned short*)(y + ((size_t)b * DIMC) * NPB) + n0;
  for (int j = tid; j < 48 * 32; j += 256) {       // stage Y (48 x 128)
    int c = j >> 5, sub = j & 31;
    ushort4 u = *(const ushort4*)(yb + (size_t)c * NPB + sub * 4);
    *(ushort2*)&Yl[c][sub * 4]     = make_ushort2(u.x, u.y);
    *(ushort2*)&Yl[c][sub * 4 + 2] = make_ushort2(u.z, u.w);
  }
  for (int j = tid; j < 16 * 32; j += 256) {       // zero rows 48..63
    int c = 48 + (j >> 5), sub = j & 31;
    *(ushort2*)&Yl[c][sub * 4]     = make_ushort2(0, 0);
    *(ushort2*)&Yl[c][sub * 4 + 2] = make_ushort2(0, 0);
  }
  if (tid < 48) {
    const float* wr = W + (size_t)(row + tid) * 48;
    unsigned short* wl = Wl[tid];
#pragma unroll
    for (int c = 0; c < 48; ++c) wl[c] = f2us(wr[c]);
#pragma unroll
    for (int c = 48; c < 64; ++c) wl[c] = 0;
  }
  __syncthreads();
  int wv = tid >> 6, ln = tid & 63, lq = ln >> 4, li = ln & 15;
  short8 afr[3][2];
#pragma unroll
  for (int mt = 0; mt < 3; ++mt)
#pragma unroll
    for (int ks = 0; ks < 2; ++ks)
      afr[mt][ks] = *(const short8*)&Wl[mt * 16 + li][ks * 32 + lq * 8];
#pragma unroll 1
  for (int ns = 0; ns < 2; ++ns) {
    int nn = wv * 32 + ns * 16 + li;
    short8 bfr[2];
#pragma unroll
    for (int ks = 0; ks < 2; ++ks)
#pragma unroll
      for (int j = 0; j < 8; ++j)
        bfr[ks][j] = (short)Yl[ks * 32 + lq * 8 + j][nn];
#pragma unroll
    for (int mt = 0; mt < 3; ++mt) {
      f32x4 acc = {0.f, 0.f, 0.f, 0.f};
      acc = __builtin_amdgcn_mfma_f32_16x16x32_bf16(afr[mt][0], bfr[0], acc, 0, 0, 0);
      acc = __builtin_amdgcn_mfma_f32_16x16x32_bf16(afr[mt][1], bfr[1], acc, 0, 0, 0);
#pragma unroll
      for (int r = 0; r < 4; ++r) {
        int m = mt * 16 + lq * 4 + r;
        dst[((size_t)b * dcs + sec * 48 + m) * NPB + n0 + nn] =
            f2fp8(16.f * (acc[r] + bias[row + m]));
      }
    }
  }
}

// ------- grouped 3x3x3 conv as block-diagonal MFMA GEMM, fp8(x16) in/out ----------
// Slab = 16 out-ch (4 groups). K = tap(dt,dh)(10, pad)*16ci = 160; dw handled by
// shifting the B-fragment row base (+dw) into the halo'd patch.
// grid (512, NSLAB): x -> b=x>>8, t=(x>>4)&15, h0=(x&15)*4 (4 h-rows per block).
__global__ __launch_bounds__(256) void k_gconv_mfma(
    const unsigned char* __restrict__ src, int sco,
    const float* __restrict__ gw, const float* __restrict__ gb,
    unsigned char* __restrict__ dst, int hp, int isV, float* __restrict__ sqout) {
  __shared__ unsigned short patch[66][168];   // [w+1 incl halo][k]  22,176 B
  __shared__ unsigned short Wl[3][16][168];   // [dw][m][k]          16,128 B
  int tid = threadIdx.x;
  int bx = blockIdx.x;
  int b = bx >> 8, t = (bx >> 4) & 15, h0 = (bx & 15) * 4;
  int s = blockIdx.y;
  int cs = s * 16;
  int seg = cs / 48, lc = cs - seg * 48;
  int wbase = isV ? 384 + (2 * hp + seg) * 48 + lc
                  : ((seg >= 2 ? 192 : 0) + (2 * hp + (seg & 1)) * 48 + lc);
  int dch = isV ? (2 * hp + seg) * 48 + lc : cs;
  const unsigned char* ib = src + ((size_t)b * 288 + sco + cs) * NPB;
  // stage weights: Wl[dw][m][tap*16+ci], zero off-group / pad-tap
  for (int j = tid; j < 7680; j += 256) {
    int dw = j / 2560, r = j - dw * 2560;
    int m = r / 160, k = r - m * 160;
    int tap = k >> 4, ci = k & 15;
    float wv = 0.f;
    if (tap < 9 && (ci >> 2) == (m >> 2)) {
      int dt = tap / 3, dh = tap - dt * 3;
      wv = gw[(size_t)(wbase + m) * 108 + (ci & 3) * 27 + dt * 9 + dh * 3 + dw];
    }
    Wl[dw][m][k] = f2us(wv);
  }
  __syncthreads();
  int ln = tid & 63, wv_ = tid >> 6, lq = ln >> 4, li = ln & 15;
  short8 afr[15];
#pragma unroll
  for (int dw = 0; dw < 3; ++dw)
#pragma unroll
    for (int ks = 0; ks < 5; ++ks)
      afr[dw * 5 + ks] = *(const short8*)&Wl[dw][li][ks * 32 + lq * 8];
  float sacc[4] = {0.f, 0.f, 0.f, 0.f};
#pragma unroll 1
  for (int hr = 0; hr < 4; ++hr) {
    int hout = h0 + hr;
    __syncthreads();
    // stage patch: rows = input w -1..64 (66), cols k = tap*16+ci (bf16 of fp8 x16)
    for (int j = tid; j < 660; j += 256) {
      if (j < 594) {
        int tap = j / 66, wr = j - tap * 66;
        int dt = tap / 3, dh = tap - dt * 3;
        int t2 = t + dt - 1, h2 = hout + dh - 1, w2 = wr - 1;
        short8 v0 = {0, 0, 0, 0, 0, 0, 0, 0};
        short8 v1 = {0, 0, 0, 0, 0, 0, 0, 0};
        if (((unsigned)t2 < 16u) && ((unsigned)h2 < 64u) && ((unsigned)w2 < 64u)) {
          const unsigned char* sp = ib + t2 * 4096 + h2 * 64 + w2;
#pragma unroll
          for (int ci = 0; ci < 8; ++ci) v0[ci] = (short)f2us(fp82f(sp[(size_t)ci * NPB]));
#pragma unroll
          for (int ci = 0; ci < 8; ++ci) v1[ci] = (short)f2us(fp82f(sp[(size_t)(ci + 8) * NPB]));
        }
        *(short8*)&patch[wr][tap * 16] = v0;
        *(short8*)&patch[wr][tap * 16 + 8] = v1;
      } else {
        int wr = j - 594;
        short8 z = {0, 0, 0, 0, 0, 0, 0, 0};
        *(short8*)&patch[wr][144] = z;
        *(short8*)&patch[wr][152] = z;
      }
    }
    __syncthreads();
    f32x4 acc = {0.f, 0.f, 0.f, 0.f};
#pragma unroll
    for (int dw = 0; dw < 3; ++dw)
#pragma unroll
      for (int ks = 0; ks < 5; ++ks) {
        short8 bfr = *(const short8*)&patch[wv_ * 16 + dw + li][ks * 32 + lq * 8];
        acc = __builtin_amdgcn_mfma_f32_16x16x32_bf16(afr[dw * 5 + ks], bfr, acc, 0, 0, 0);
      }
    size_t obase = ((size_t)b * 192 + dch) * NPB + t * 4096 + hout * 64 + wv_ * 16 + li;
#pragma unroll
    for (int r = 0; r < 4; ++r) {
      int m = lq * 4 + r;
      unsigned char rv = f2fp8(acc[r] + 16.f * gb[wbase + m]);
      dst[obase + (size_t)m * NPB] = rv;
      if (sqout) { float f = fp82f(rv); sacc[r] = fmaf(f, f, sacc[r]); }
    }
  }
  if (sqout) {
#pragma unroll
    for (int r = 0; r < 4; ++r) {
      float sv = sacc[r];
      sv += __shfl_down(sv, 8);
      sv += __shfl_down(sv, 4);
      sv += __shfl_down(sv, 2);
      sv += __shfl_down(sv, 1);
      if (li == 0) {
        int m = lq * 4 + r;
        int sqi = (seg < 2 ? 0 : 384) + b * 192 + (2 * hp + (seg & 1)) * 48 + lc + m;
        atomicAdd(&sqout[sqi], sv);
      }
    }
  }
}

// ---------------- MFMA Gram from fp8 q,k (x16): scale cancels with norms ----------
// grid (64, 2, 2): x = 1024-wide n-chunk, y = batch, z = head-in-pair.
__global__ __launch_bounds__(256) void k_gram_mfma(
    const unsigned char* __restrict__ qkd, int hp, float* __restrict__ Gm) {
  __shared__ unsigned short qkl[2][48][264];
  int tid = threadIdx.x, b = blockIdx.y, z = blockIdx.z;
  int wv = tid >> 6, ln = tid & 63, lq = ln >> 4, li = ln & 15;
  const unsigned char* qb = qkd + ((size_t)b * 192 + z * 48) * NPB + blockIdx.x * 1024;
  const unsigned char* kb = qkd + ((size_t)b * 192 + 96 + z * 48) * NPB + blockIdx.x * 1024;
  f32x4 acc[9];
#pragma unroll
  for (int t = 0; t < 9; ++t) acc[t] = (f32x4){0.f, 0.f, 0.f, 0.f};
#pragma unroll 1
  for (int it = 0; it < 4; ++it) {
    __syncthreads();
    for (int j = tid; j < 48 * 64; j += 256) {
      int c = j >> 6, sub = j & 63;
      uchar4 uq = *(const uchar4*)(qb + (size_t)c * NPB + it * 256 + sub * 4);
      uchar4 uk = *(const uchar4*)(kb + (size_t)c * NPB + it * 256 + sub * 4);
      *(ushort2*)&qkl[0][c][sub * 4]     = make_ushort2(f2us(fp82f(uq.x)), f2us(fp82f(uq.y)));
      *(ushort2*)&qkl[0][c][sub * 4 + 2] = make_ushort2(f2us(fp82f(uq.z)), f2us(fp82f(uq.w)));
      *(ushort2*)&qkl[1][c][sub * 4]     = make_ushort2(f2us(fp82f(uk.x)), f2us(fp82f(uk.y)));
      *(ushort2*)&qkl[1][c][sub * 4 + 2] = make_ushort2(f2us(fp82f(uk.z)), f2us(fp82f(uk.w)));
    }
    __syncthreads();
    short8 afr[3][2], bfr[3][2];
#pragma unroll
    for (int ks = 0; ks < 2; ++ks) {
      int kbase = wv * 64 + ks * 32 + lq * 8;
#pragma unroll
      for (int t = 0; t < 3; ++t) {
        afr[t][ks] = *(const short8*)&qkl[0][t * 16 + li][kbase];
        bfr[t][ks] = *(const short8*)&qkl[1][t * 16 + li][kbase];
      }
    }
#pragma unroll
    for (int mt = 0; mt < 3; ++mt)
#pragma unroll
      for (int nt = 0; nt < 3; ++nt) {
        acc[mt * 3 + nt] = __builtin_amdgcn_mfma_f32_16x16x32_bf16(afr[mt][0], bfr[nt][0], acc[mt * 3 + nt], 0, 0, 0);
        acc[mt * 3 + nt] = __builtin_amdgcn_mfma_f32_16x16x32_bf16(afr[mt][1], bfr[nt][1], acc[mt * 3 + nt], 0, 0, 0);
      }
  }
  __syncthreads();
  float* red = (float*)&qkl[0][0][0];
  if (wv > 0) {
    float* rw = red + (size_t)(wv - 1) * 2304;
#pragma unroll
    for (int t = 0; t < 9; ++t)
#pragma unroll
      for (int r = 0; r < 4; ++r)
        rw[t * 256 + r * 64 + ln] = acc[t][r];
  }
  __syncthreads();
  if (wv == 0) {
    int hd = 2 * hp + z;
    float* gbase = Gm + (size_t)(b * 4 + hd) * 2304;
#pragma unroll
    for (int t = 0; t < 9; ++t) {
      int mt = t / 3, nt = t - mt * 3;
#pragma unroll
      for (int r = 0; r < 4; ++r) {
        int o = t * 256 + r * 64 + ln;
        float v = acc[t][r] + red[o] + red[2304 + o] + red[4608 + o];
        atomicAdd(&gbase[(mt * 16 + lq * 4 + r) * 48 + nt * 16 + li], v);
      }
    }
  }
}

// ------- tiny: per-(b,head) softmax(norm G) + proj fold -> Mm[b][48][192] bf16 ----
__global__ __launch_bounds__(256) void k_attn_mm(
    const float* __restrict__ Gm, const float* __restrict__ sq, const float* __restrict__ temp,
    const float* __restrict__ pw, bf16* __restrict__ Mm) {
  __shared__ float A[48][48];
  __shared__ float nk[48];
  int tid = threadIdx.x;
  int bh = blockIdx.x; int b = bh >> 2, hd = bh & 3;
  if (tid >= 64 && tid < 112)
    nk[tid - 64] = fmaxf(sqrtf(sq[384 + bh * 48 + tid - 64]), 1e-12f);
  __syncthreads();
  if (tid < 48) {
    float tv = temp[hd];
    float rq = 1.f / fmaxf(sqrtf(sq[bh * 48 + tid]), 1e-12f);
    const float* grow = Gm + (size_t)bh * 2304 + tid * 48;
    float mx = -1e30f;
#pragma unroll
    for (int d = 0; d < 48; ++d) mx = fmaxf(mx, grow[d] * rq / nk[d] * tv);
    float sum = 0.f;
#pragma unroll
    for (int d = 0; d < 48; ++d) {
      float e = expf(grow[d] * rq / nk[d] * tv - mx);
      A[tid][d] = e; sum += e;
    }
    float inv = 1.f / sum;
#pragma unroll
    for (int d = 0; d < 48; ++d) A[tid][d] *= inv;
  }
  __syncthreads();
  for (int j = tid; j < 2304; j += 256) {
    int m = j / 48, d = j - m * 48;
    float a = 0.f;
#pragma unroll
    for (int c = 0; c < 48; ++c) a = fmaf(pw[m * 192 + hd * 48 + c], A[c][d], a);
    Mm[((size_t)b * 48 + m) * 192 + hd * 48 + d] = f2b(a * 0.0625f);
  }
}

// ------- K=192 GEMM: out = x + pb + Mm[b] @ v8[b]  (fp8 v, bf16 MFMA) -------------
__global__ __launch_bounds__(256) void k_av192(
    const unsigned char* __restrict__ vd8, const bf16* __restrict__ Mm,
    const float* __restrict__ pb, const float* __restrict__ x, float* __restrict__ outp) {
  __shared__ unsigned short Yl[96][130];
  __shared__ unsigned short Ml[48][200];
  int tid = threadIdx.x;
  int bt = blockIdx.x;
  int b = bt >> 9;
  int n0 = (bt & 511) * 128;
  int wv = tid >> 6, ln = tid & 63, lq = ln >> 4, li = ln & 15;
  const unsigned short* mb = (const unsigned short*)(Mm + (size_t)b * 48 * 192);
  for (int j = tid; j < 48 * 48; j += 256) {       // stage M (48 x 192)
    int m = j / 48, c4 = j - m * 48;
    *(ushort4*)&Ml[m][c4 * 4] = *(const ushort4*)(mb + m * 192 + c4 * 4);
  }
  const unsigned char* vb = vd8 + ((size_t)b * C2) * NPB + n0;
  f32x4 acc[3][2];
#pragma unroll
  for (int mt = 0; mt < 3; ++mt)
#pragma unroll
    for (int ns = 0; ns < 2; ++ns) acc[mt][ns] = (f32x4){0.f, 0.f, 0.f, 0.f};
#pragma unroll 1
  for (int s = 0; s < 2; ++s) {
    __syncthreads();
    for (int j = tid; j < 96 * 32; j += 256) {     // stage V half (96 x 128), decode
      int c = j >> 5, sub = j & 31;
      uchar4 u = *(const uchar4*)(vb + (size_t)(s * 96 + c) * NPB + sub * 4);
      *(ushort2*)&Yl[c][sub * 4]     = make_ushort2(f2us(fp82f(u.x)), f2us(fp82f(u.y)));
      *(ushort2*)&Yl[c][sub * 4 + 2] = make_ushort2(f2us(fp82f(u.z)), f2us(fp82f(u.w)));
    }
    __syncthreads();
#pragma unroll 1
    for (int ns = 0; ns < 2; ++ns) {
      int nn = wv * 32 + ns * 16 + li;
      short8 bfr[3];
#pragma unroll
      for (int ks = 0; ks < 3; ++ks)
#pragma unroll
        for (int j = 0; j < 8; ++j)
          bfr[ks][j] = (short)Yl[ks * 32 + lq * 8 + j][nn];
#pragma unroll
      for (int mt = 0; mt < 3; ++mt) {
        short8 a0 = *(const short8*)&Ml[mt * 16 + li][s * 96 + lq * 8];
        short8 a1 = *(const short8*)&Ml[mt * 16 + li][s * 96 + 32 + lq * 8];
        short8 a2 = *(const short8*)&Ml[mt * 16 + li][s * 96 + 64 + lq * 8];
        acc[mt][ns] = __builtin_amdgcn_mfma_f32_16x16x32_bf16(a0, bfr[0], acc[mt][ns], 0, 0, 0);
        acc[mt][ns] = __builtin_amdgcn_mfma_f32_16x16x32_bf16(a1, bfr[1], acc[mt][ns], 0, 0, 0);
        acc[mt][ns] = __builtin_amdgcn_mfma_f32_16x16x32_bf16(a2, bfr[2], acc[mt][ns], 0, 0, 0);
      }
    }
  }
#pragma unroll
  for (int ns = 0; ns < 2; ++ns) {
    int nn = wv * 32 + ns * 16 + li;
#pragma unroll
    for (int mt = 0; mt < 3; ++mt)
#pragma unroll
      for (int r = 0; r < 4; ++r) {
        int m = mt * 16 + lq * 4 + r;
        size_t idx = ((size_t)b * DIMC + m) * NPB + n0 + nn;
        outp[idx] = x[idx] + pb[m] + acc[mt][ns][r];
      }
  }
}

// ---------------- MFMA K=96 GEMM (pout), fp8(x16) input: out = addend+bias+W@g ----
__global__ __launch_bounds__(256) void k_ek96(
    const unsigned char* __restrict__ V, const float* __restrict__ W, int wrs,
    const float* __restrict__ bias, const float* __restrict__ addend, float* __restrict__ outp) {
  __shared__ unsigned short Yl[96][130];
  __shared__ unsigned short Wl[48][104];
  int tid = threadIdx.x;
  int bt = blockIdx.x;
  int b = bt >> 9;
  int n0 = (bt & 511) * 128;
  const unsigned char* vb = V + ((size_t)b * 96) * NPB + n0;
  for (int j = tid; j < 96 * 32; j += 256) {
    int c = j >> 5, sub = j & 31;
    uchar4 u = *(const uchar4*)(vb + (size_t)c * NPB + sub * 4);
    *(ushort2*)&Yl[c][sub * 4]     = make_ushort2(f2us(fp82f(u.x)), f2us(fp82f(u.y)));
    *(ushort2*)&Yl[c][sub * 4 + 2] = make_ushort2(f2us(fp82f(u.z)), f2us(fp82f(u.w)));
  }
  if (tid < 48) {
    const float* wr = W + (size_t)tid * wrs;
    unsigned short* wl = Wl[tid];
#pragma unroll
    for (int c = 0; c < 96; ++c) wl[c] = f2us(wr[c] * 0.0625f);   // cancel x16
  }
  __syncthreads();
  int wv = tid >> 6, ln = tid & 63, lq = ln >> 4, li = ln & 15;
  short8 afr[3][3];
#pragma unroll
  for (int mt = 0; mt < 3; ++mt)
#pragma unroll
    for (int ks = 0; ks < 3; ++ks)
      afr[mt][ks] = *(const short8*)&Wl[mt * 16 + li][ks * 32 + lq * 8];
#pragma unroll 1
  for (int ns = 0; ns < 2; ++ns) {
    int nn = wv * 32 + ns * 16 + li;
    short8 bfr[3];
#pragma unroll
    for (int ks = 0; ks < 3; ++ks)
#pragma unroll
      for (int j = 0; j < 8; ++j)
        bfr[ks][j] = (short)Yl[ks * 32 + lq * 8 + j][nn];
#pragma unroll
    for (int mt = 0; mt < 3; ++mt) {
      f32x4 acc = {0.f, 0.f, 0.f, 0.f};
      acc = __builtin_amdgcn_mfma_f32_16x16x32_bf16(afr[mt][0], bfr[0], acc, 0, 0, 0);
      acc = __builtin_amdgcn_mfma_f32_16x16x32_bf16(afr[mt][1], bfr[1], acc, 0, 0, 0);
      acc = __builtin_amdgcn_mfma_f32_16x16x32_bf16(afr[mt][2], bfr[2], acc, 0, 0, 0);
#pragma unroll
      for (int r = 0; r < 4; ++r) {
        int m = mt * 16 + lq * 4 + r;
        size_t idx = ((size_t)b * DIMC + m) * NPB + n0 + nn;
        outp[idx] = acc[r] + addend[idx] + bias[m];
      }
    }
  }
}

// ------- depthwise 3x3x3 + GELU gate; f32-LDS (1 ch/pass), split-w columns --------
// grid (32, 96, 2): x = t-tile(8) x h-tile(4) [2t x 16h x 64w], y = ch pair.
__global__ __launch_bounds__(256) void k_dw_gelu(
    const unsigned char* __restrict__ z, const float* __restrict__ dwW,
    const float* __restrict__ dwB, unsigned char* __restrict__ g) {
  __shared__ float tile[4][18][68];      // one ch per pass: 19,584 B
  int tid = threadIdx.x;
  int t0 = (blockIdx.x >> 2) * 2, h0 = (blockIdx.x & 3) * 16;
  int c = blockIdx.y, b = blockIdx.z;
  int wp = tid & 31, hq = tid >> 5;
  float a[2][2][2][2];                   // [ch][t][i][wg]
#pragma unroll
  for (int ch = 0; ch < 2; ++ch)
#pragma unroll
    for (int t = 0; t < 2; ++t)
#pragma unroll
      for (int i = 0; i < 2; ++i) { a[ch][t][i][0] = 0.f; a[ch][t][i][1] = 0.f; }
#pragma unroll 1
  for (int ch = 0; ch < 2; ++ch) {
    const unsigned char* zp = z + ((size_t)b * C2 + c + ch * HIDC) * NPB;
    __syncthreads();
    for (int j = tid; j < 72 * 16; j += 256) {     // stage 4tt x 18hh x 64w
      int r = j >> 4, sub = j & 15;
      int tt = r / 18, hh = r - tt * 18;
      int gt = t0 + tt - 1, gh = h0 + hh - 1;
      float* dp = &tile[tt][hh][1 + sub * 4];
      if ((unsigned)gt < 16u && (unsigned)gh < 64u) {
        uchar4 u = *(const uchar4*)(zp + gt * 4096 + gh * 64 + sub * 4);
        dp[0] = fp82f(u.x); dp[1] = fp82f(u.y); dp[2] = fp82f(u.z); dp[3] = fp82f(u.w);
      } else { dp[0] = 0.f; dp[1] = 0.f; dp[2] = 0.f; dp[3] = 0.f; }
    }
    for (int j = tid; j < 144; j += 256) {
      int r = j >> 1, side = j & 1;
      int tt = r / 18, hh = r - tt * 18;
      tile[tt][hh][side ? 65 : 0] = 0.f;
    }
    __syncthreads();
    const float* wt = dwW + (size_t)(c + ch * HIDC) * 27;
#pragma unroll
    for (int wg = 0; wg < 2; ++wg) {
      int w0 = wp + wg * 32;
      float v[4][4][3];
#pragma unroll
      for (int tt = 0; tt < 4; ++tt)
#pragma unroll
        for (int rr = 0; rr < 4; ++rr)
#pragma unroll
          for (int dc = 0; dc < 3; ++dc)
            v[tt][rr][dc] = tile[tt][2 * hq + rr][w0 + dc];
#pragma unroll
      for (int dt = 0; dt < 3; ++dt)
#pragma unroll
        for (int dh = 0; dh < 3; ++dh)
#pragma unroll
          for (int dw = 0; dw < 3; ++dw) {
            float wv = wt[dt * 9 + dh * 3 + dw];
#pragma unroll
            for (int t = 0; t < 2; ++t)
#pragma unroll
              for (int i = 0; i < 2; ++i)
                a[ch][t][i][wg] = fmaf(wv, v[t + dt][i + dh][dw], a[ch][t][i][wg]);
          }
    }
  }
  float b1 = dwB[c], b2v = dwB[c + HIDC];
  size_t obase = ((size_t)b * HIDC + c) * NPB;
#pragma unroll
  for (int t = 0; t < 2; ++t)
#pragma unroll
    for (int i = 0; i < 2; ++i)
#pragma unroll
      for (int wg = 0; wg < 2; ++wg) {
        float x1v = a[0][t][i][wg] * 0.0625f + b1;
        float x2v = a[1][t][i][wg] * 0.0625f + b2v;
        float ge = 0.5f * x1v * (1.f + erff(x1v * 0.70710678118654752f));
        g[obase + (t0 + t) * 4096 + (h0 + 2 * hq + i) * 64 + wp + wg * 32] =
            f2fp8(16.f * ge * x2v);
      }
}

extern "C" void kernel_launch(void* const* d_in, const int* in_sizes, int n_in,
                              void* d_out, int out_size, void* d_ws, size_t ws_size,
                              hipStream_t stream) {
  (void)in_sizes; (void)n_in; (void)out_size; (void)ws_size;
  const float* x     = (const float*)d_in[0];
  const float* ln1w  = (const float*)d_in[1];
  const float* ln1b  = (const float*)d_in[2];
  const float* qkvw  = (const float*)d_in[3];
  const float* qkvb  = (const float*)d_in[4];
  const float* gdww  = (const float*)d_in[5];
  const float* gdwb  = (const float*)d_in[6];
  const float* temp  = (const float*)d_in[7];
  const float* projw = (const float*)d_in[8];
  const float* projb = (const float*)d_in[9];
  const float* ln2w  = (const float*)d_in[10];
  const float* ln2b  = (const float*)d_in[11];
  const float* pinw  = (const float*)d_in[12];
  const float* pinb  = (const float*)d_in[13];
  const float* dww   = (const float*)d_in[14];
  const float* dwb   = (const float*)d_in[15];
  const float* poutw = (const float*)d_in[16];
  const float* poutb = (const float*)d_in[17];
  float* out = (float*)d_out;

  // Workspace: y 12.6M | st288 37.7M | vd8 25.2M | Gm/sq/Mm tail -> 75.61M (proven)
  // qkd8 lives in d_out (exactly 25,165,824 B), dead before k_av192 writes out.
  char* ws = (char*)d_ws;
  bf16*  y     = (bf16*)(ws);                              // 12,582,912 B
  unsigned char* st288 = (unsigned char*)(ws + 12582912);  // 37,748,736 B [2][288][NPB]
  unsigned char* vd8   = (unsigned char*)(ws + 50331648);  // 25,165,824 B [2][192][NPB]
  float* Gm    = (float*)(ws + 75497472);                  //     73,728 B
  float* sq    = (float*)(ws + 75571200);                  //      3,072 B
  bf16*  Mm    = (bf16*)(ws + 75574272);                   //     36,864 B
  unsigned char* qkd8 = (unsigned char*)d_out;             // 25,165,824 B (scratch)
  // FFN phase (attention buffers dead):
  bf16*  y2    = (bf16*)(ws);                              // 12,582,912 B
  unsigned char* z8  = (unsigned char*)(ws + 12582912);    // 25,165,824 B
  unsigned char* gg8 = (unsigned char*)(ws + 37748736);    // 12,582,912 B

  hipMemsetAsync(Gm, 0, 73728 + 3072, stream);
  k_ln<<<dim3(512), dim3(256), 0, stream>>>(x, ln1w, ln1b, y);

  for (int hp = 0; hp < 2; ++hp) {
    // q,k,v pointwise for head pair (6 sections), fp8 out -> st288
    k_pconv_sec<<<dim3(6, 1024), dim3(256), 0, stream>>>(y, qkvw, qkvb, hp, st288, 288);
    // grouped dw-conv q+k (192 ch, 12 slabs) -> qkd8 (in d_out) + sumsq  [MFMA]
    k_gconv_mfma<<<dim3(512, 12), dim3(256), 0, stream>>>(
        st288, 0, gdww, gdwb, qkd8, hp, 0, sq);
    // Gram for both heads of the pair
    k_gram_mfma<<<dim3(64, 2, 2), dim3(256), 0, stream>>>(qkd8, hp, Gm);
    // grouped dw-conv v (96 ch, 6 slabs) -> vd8 slots  [MFMA]
    k_gconv_mfma<<<dim3(512, 6), dim3(256), 0, stream>>>(
        st288, 192, gdww, gdwb, vd8, hp, 1, nullptr);
  }
  k_attn_mm<<<dim3(8), dim3(256), 0, stream>>>(Gm, sq, temp, projw, Mm);
  k_av192<<<dim3(1024), dim3(256), 0, stream>>>(vd8, Mm, projb, x, out);

  k_ln<<<dim3(512), dim3(256), 0, stream>>>(out, ln2w, ln2b, y2);
  k_pconv_sec<<<dim3(4, 1024), dim3(256), 0, stream>>>(y2, pinw, pinb, -1, z8, 192);
  k_dw_gelu<<<dim3(32, 96, 2), dim3(256), 0, stream>>>(z8, dww, dwb, gg8);
  k_ek96<<<dim3(1024), dim3(256), 0, stream>>>(gg8, poutw, 96, poutb, out, out);
}

// Round 11
// 709.929 us; speedup vs baseline: 1.6948x; 1.6948x over previous
//
#include <hip/hip_runtime.h>
#include <hip/hip_bf16.h>
#include <hip/hip_fp8.h>
#include <math.h>

typedef __hip_bfloat16 bf16;
typedef __attribute__((ext_vector_type(8))) short short8;
typedef __attribute__((ext_vector_type(4))) float f32x4;

#define NPB   65536   // positions per batch (16*64*64)
#define DIMC  48
#define C2    192
#define HIDC  96
#define TT    16

static __device__ __forceinline__ float b2f(bf16 v) { return __bfloat162float(v); }
static __device__ __forceinline__ bf16  f2b(float v) { return __float2bfloat16(v); }
static __device__ __forceinline__ float bfr2f(unsigned short u) {
  union { unsigned int i; float f; } c; c.i = ((unsigned int)u) << 16; return c.f;
}
static __device__ __forceinline__ unsigned short f2us(float v) {
  return __bfloat16_as_ushort(__float2bfloat16(v));
}
static __device__ __forceinline__ unsigned char f2fp8(float v) {
  __hip_fp8_e4m3 t(v); return (unsigned char)t.__x;
}
static __device__ __forceinline__ float fp82f(unsigned char u) {
  __hip_fp8_e4m3 t; t.__x = (__hip_fp8_storage_t)u; return (float)t;
}

// ---------------- y = LN(x) over 48 channels, bf16 out (LN1 and LN2) -------------
__global__ __launch_bounds__(256) void k_ln(
    const float* __restrict__ x, const float* __restrict__ lw, const float* __restrict__ lb,
    bf16* __restrict__ y) {
  int p = blockIdx.x * 256 + threadIdx.x;   // 0..131071
  int b = p >> 16, n = p & (NPB - 1);
  const float* xb = x + ((size_t)b * DIMC) * NPB + n;
  float v[DIMC]; float s = 0.f, s2 = 0.f;
#pragma unroll
  for (int c = 0; c < DIMC; ++c) { float t = xb[(size_t)c * NPB]; v[c] = t; s += t; s2 += t * t; }
  float mu = s * (1.f / DIMC);
  float var = fmaxf(s2 * (1.f / DIMC) - mu * mu, 0.f);
  float rs = rsqrtf(var + 1e-5f);
  bf16* yb = y + ((size_t)b * DIMC) * NPB + n;
#pragma unroll
  for (int c = 0; c < DIMC; ++c) yb[(size_t)c * NPB] = f2b((v[c] - mu) * rs * lw[c] + lb[c]);
}

// ------- MFMA 1x1 conv, sectioned, fp8(x16) out. grid (NSEC, 1024) ----------------
// hp >= 0: qkv head-pair mapping (sec 0..5 -> q(2hp),q(2hp+1),k0,k1,v0,v1)
// hp <  0: plain rows sec*48 (FFN pin).
__global__ __launch_bounds__(256) void k_pconv_sec(
    const bf16* __restrict__ y, const float* __restrict__ W,
    const float* __restrict__ bias, int hp, unsigned char* __restrict__ dst, int dcs) {
  __shared__ unsigned short Yl[64][130];
  __shared__ unsigned short Wl[48][72];
  int tid = threadIdx.x;
  int sec = blockIdx.x;
  int row = (hp >= 0) ? ((sec >> 1) * 192 + (2 * hp + (sec & 1)) * 48) : sec * 48;
  int bt = blockIdx.y;
  int b = bt >> 9;
  int n0 = (bt & 511) * 128;
  const unsigned short* yb = (const unsigned short*)(y + ((size_t)b * DIMC) * NPB) + n0;
  for (int j = tid; j < 48 * 32; j += 256) {       // stage Y (48 x 128)
    int c = j >> 5, sub = j & 31;
    ushort4 u = *(const ushort4*)(yb + (size_t)c * NPB + sub * 4);
    *(ushort2*)&Yl[c][sub * 4]     = make_ushort2(u.x, u.y);
    *(ushort2*)&Yl[c][sub * 4 + 2] = make_ushort2(u.z, u.w);
  }
  for (int j = tid; j < 16 * 32; j += 256) {       // zero rows 48..63
    int c = 48 + (j >> 5), sub = j & 31;
    *(ushort2*)&Yl[c][sub * 4]     = make_ushort2(0, 0);
    *(ushort2*)&Yl[c][sub * 4 + 2] = make_ushort2(0, 0);
  }
  if (tid < 48) {
    const float* wr = W + (size_t)(row + tid) * 48;
    unsigned short* wl = Wl[tid];
#pragma unroll
    for (int c = 0; c < 48; ++c) wl[c] = f2us(wr[c]);
#pragma unroll
    for (int c = 48; c < 64; ++c) wl[c] = 0;
  }
  __syncthreads();
  int wv = tid >> 6, ln = tid & 63, lq = ln >> 4, li = ln & 15;
  short8 afr[3][2];
#pragma unroll
  for (int mt = 0; mt < 3; ++mt)
#pragma unroll
    for (int ks = 0; ks < 2; ++ks)
      afr[mt][ks] = *(const short8*)&Wl[mt * 16 + li][ks * 32 + lq * 8];
#pragma unroll 1
  for (int ns = 0; ns < 2; ++ns) {
    int nn = wv * 32 + ns * 16 + li;
    short8 bfr[2];
#pragma unroll
    for (int ks = 0; ks < 2; ++ks)
#pragma unroll
      for (int j = 0; j < 8; ++j)
        bfr[ks][j] = (short)Yl[ks * 32 + lq * 8 + j][nn];
#pragma unroll
    for (int mt = 0; mt < 3; ++mt) {
      f32x4 acc = {0.f, 0.f, 0.f, 0.f};
      acc = __builtin_amdgcn_mfma_f32_16x16x32_bf16(afr[mt][0], bfr[0], acc, 0, 0, 0);
      acc = __builtin_amdgcn_mfma_f32_16x16x32_bf16(afr[mt][1], bfr[1], acc, 0, 0, 0);
#pragma unroll
      for (int r = 0; r < 4; ++r) {
        int m = mt * 16 + lq * 4 + r;
        dst[((size_t)b * dcs + sec * 48 + m) * NPB + n0 + nn] =
            f2fp8(16.f * (acc[r] + bias[row + m]));
      }
    }
  }
}

// ------- grouped 3x3x3 conv, u16-bf16 LDS tile + LDS-staged weights, fp8 in/out ---
// grid (32, NG, 2): x = t-tile(8) x h-tile(4) [2t x 16h x 64w], y = 4-ch group.
// Thread: w = tid&63 (full row), hr = tid>>6 -> 4 h-rows; 32 outputs/thread.
__global__ __launch_bounds__(256) void k_gconv48(
    const unsigned char* __restrict__ src, int sco,
    const float* __restrict__ gw, const float* __restrict__ gb,
    unsigned char* __restrict__ dst, int hp, int isV, float* __restrict__ sqout) {
  __shared__ unsigned short tile[4][4][18][66];   // 19,008 B
  __shared__ float Wf[432];                       //  1,728 B [ci][27 taps][4 oc]
  __shared__ float red[4][4];
  int tid = threadIdx.x;
  int t0 = (blockIdx.x >> 2) * 2, h0 = (blockIdx.x & 3) * 16;
  int cbase = blockIdx.y * 4, b = blockIdx.z;
  int seg = cbase / 48, lc = cbase - seg * 48;
  int wbase = isV ? 384 + (2 * hp + seg) * 48 + lc
                  : ((seg >= 2 ? 192 : 0) + (2 * hp + (seg & 1)) * 48 + lc);
  int dch = isV ? (2 * hp + seg) * 48 + lc : cbase;
  const unsigned char* ib = src + ((size_t)b * 288 + sco + cbase) * NPB;
  for (int j = tid; j < 432; j += 256) {          // stage weights once
    int o = j & 3, tc = j >> 2;
    int ci = tc / 27, tap = tc - ci * 27;
    Wf[j] = gw[(size_t)(wbase + o) * 108 + ci * 27 + tap];
  }
  for (int j = tid; j < 288 * 16; j += 256) {     // stage 4ci x 4tt x 18hh x 64w
    int r = j >> 4, sub = j & 15;
    int ci = r / 72, rem = r - ci * 72;
    int tt = rem / 18, hh = rem - tt * 18;
    int gt = t0 + tt - 1, gh2 = h0 + hh - 1;
    unsigned short* dp = &tile[ci][tt][hh][1 + sub * 4];
    if ((unsigned)gt < 16u && (unsigned)gh2 < 64u) {
      uchar4 u = *(const uchar4*)(ib + (size_t)ci * NPB + gt * 4096 + gh2 * 64 + sub * 4);
      dp[0] = f2us(fp82f(u.x)); dp[1] = f2us(fp82f(u.y));
      dp[2] = f2us(fp82f(u.z)); dp[3] = f2us(fp82f(u.w));
    } else { dp[0] = 0; dp[1] = 0; dp[2] = 0; dp[3] = 0; }
  }
  for (int j = tid; j < 576; j += 256) {          // w halos
    int r = j >> 1, side = j & 1;
    int ci = r / 72, rem = r - ci * 72;
    int tt = rem / 18, hh = rem - tt * 18;
    tile[ci][tt][hh][side ? 65 : 0] = 0;
  }
  __syncthreads();
  int w = tid & 63, hr = tid >> 6;
  float acc[2][4][4];                             // [t][i(h)][oc]
#pragma unroll
  for (int t = 0; t < 2; ++t)
#pragma unroll
    for (int i = 0; i < 4; ++i)
#pragma unroll
      for (int o = 0; o < 4; ++o) acc[t][i][o] = 0.f;
#pragma unroll 1
  for (int ci = 0; ci < 4; ++ci) {
#pragma unroll 1
    for (int dw = 0; dw < 3; ++dw) {
      int wwl = w + dw;
      float v[4][6];
#pragma unroll
      for (int tt = 0; tt < 4; ++tt)
#pragma unroll
        for (int r = 0; r < 6; ++r) v[tt][r] = bfr2f(tile[ci][tt][hr * 4 + r][wwl]);
#pragma unroll
      for (int dt = 0; dt < 3; ++dt)
#pragma unroll
        for (int dh = 0; dh < 3; ++dh) {
          float4 wv = *(const float4*)&Wf[(ci * 27 + dt * 9 + dh * 3 + dw) * 4];
#pragma unroll
          for (int t = 0; t < 2; ++t)
#pragma unroll
            for (int i = 0; i < 4; ++i) {
              float val = v[t + dt][i + dh];
              acc[t][i][0] = fmaf(wv.x, val, acc[t][i][0]);
              acc[t][i][1] = fmaf(wv.y, val, acc[t][i][1]);
              acc[t][i][2] = fmaf(wv.z, val, acc[t][i][2]);
              acc[t][i][3] = fmaf(wv.w, val, acc[t][i][3]);
            }
        }
    }
  }
  float s[4] = {0.f, 0.f, 0.f, 0.f};
#pragma unroll
  for (int o = 0; o < 4; ++o) {
    float bias16 = 16.f * gb[wbase + o];
    size_t obase = ((size_t)b * 192 + dch + o) * NPB;
#pragma unroll
    for (int t = 0; t < 2; ++t)
#pragma unroll
      for (int i = 0; i < 4; ++i) {
        unsigned char rv = f2fp8(acc[t][i][o] + bias16);
        dst[obase + (t0 + t) * 4096 + (h0 + hr * 4 + i) * 64 + w] = rv;
        if (sqout) { float f = fp82f(rv); s[o] = fmaf(f, f, s[o]); }
      }
  }
  if (sqout) {
#pragma unroll
    for (int o = 0; o < 4; ++o) {
      float sv = s[o];
#pragma unroll
      for (int off = 32; off; off >>= 1) sv += __shfl_down(sv, off);
      if ((tid & 63) == 0) red[tid >> 6][o] = sv;
    }
    __syncthreads();
    if (tid < 4) {
      int sqi = (seg < 2 ? 0 : 384) + b * 192 + (2 * hp + (seg & 1)) * 48 + lc + tid;
      atomicAdd(&sqout[sqi], red[0][tid] + red[1][tid] + red[2][tid] + red[3][tid]);
    }
  }
}

// ---------------- MFMA Gram from fp8 q,k (x16): scale cancels with norms ----------
// grid (64, 2, 2): x = 1024-wide n-chunk, y = batch, z = head-in-pair.
__global__ __launch_bounds__(256) void k_gram_mfma(
    const unsigned char* __restrict__ qkd, int hp, float* __restrict__ Gm) {
  __shared__ unsigned short qkl[2][48][264];
  int tid = threadIdx.x, b = blockIdx.y, z = blockIdx.z;
  int wv = tid >> 6, ln = tid & 63, lq = ln >> 4, li = ln & 15;
  const unsigned char* qb = qkd + ((size_t)b * 192 + z * 48) * NPB + blockIdx.x * 1024;
  const unsigned char* kb = qkd + ((size_t)b * 192 + 96 + z * 48) * NPB + blockIdx.x * 1024;
  f32x4 acc[9];
#pragma unroll
  for (int t = 0; t < 9; ++t) acc[t] = (f32x4){0.f, 0.f, 0.f, 0.f};
#pragma unroll 1
  for (int it = 0; it < 4; ++it) {
    __syncthreads();
    for (int j = tid; j < 48 * 64; j += 256) {
      int c = j >> 6, sub = j & 63;
      uchar4 uq = *(const uchar4*)(qb + (size_t)c * NPB + it * 256 + sub * 4);
      uchar4 uk = *(const uchar4*)(kb + (size_t)c * NPB + it * 256 + sub * 4);
      *(ushort2*)&qkl[0][c][sub * 4]     = make_ushort2(f2us(fp82f(uq.x)), f2us(fp82f(uq.y)));
      *(ushort2*)&qkl[0][c][sub * 4 + 2] = make_ushort2(f2us(fp82f(uq.z)), f2us(fp82f(uq.w)));
      *(ushort2*)&qkl[1][c][sub * 4]     = make_ushort2(f2us(fp82f(uk.x)), f2us(fp82f(uk.y)));
      *(ushort2*)&qkl[1][c][sub * 4 + 2] = make_ushort2(f2us(fp82f(uk.z)), f2us(fp82f(uk.w)));
    }
    __syncthreads();
    short8 afr[3][2], bfr[3][2];
#pragma unroll
    for (int ks = 0; ks < 2; ++ks) {
      int kbase = wv * 64 + ks * 32 + lq * 8;
#pragma unroll
      for (int t = 0; t < 3; ++t) {
        afr[t][ks] = *(const short8*)&qkl[0][t * 16 + li][kbase];
        bfr[t][ks] = *(const short8*)&qkl[1][t * 16 + li][kbase];
      }
    }
#pragma unroll
    for (int mt = 0; mt < 3; ++mt)
#pragma unroll
      for (int nt = 0; nt < 3; ++nt) {
        acc[mt * 3 + nt] = __builtin_amdgcn_mfma_f32_16x16x32_bf16(afr[mt][0], bfr[nt][0], acc[mt * 3 + nt], 0, 0, 0);
        acc[mt * 3 + nt] = __builtin_amdgcn_mfma_f32_16x16x32_bf16(afr[mt][1], bfr[nt][1], acc[mt * 3 + nt], 0, 0, 0);
      }
  }
  __syncthreads();
  float* red = (float*)&qkl[0][0][0];
  if (wv > 0) {
    float* rw = red + (size_t)(wv - 1) * 2304;
#pragma unroll
    for (int t = 0; t < 9; ++t)
#pragma unroll
      for (int r = 0; r < 4; ++r)
        rw[t * 256 + r * 64 + ln] = acc[t][r];
  }
  __syncthreads();
  if (wv == 0) {
    int hd = 2 * hp + z;
    float* gbase = Gm + (size_t)(b * 4 + hd) * 2304;
#pragma unroll
    for (int t = 0; t < 9; ++t) {
      int mt = t / 3, nt = t - mt * 3;
#pragma unroll
      for (int r = 0; r < 4; ++r) {
        int o = t * 256 + r * 64 + ln;
        float v = acc[t][r] + red[o] + red[2304 + o] + red[4608 + o];
        atomicAdd(&gbase[(mt * 16 + lq * 4 + r) * 48 + nt * 16 + li], v);
      }
    }
  }
}

// ------- tiny: per-(b,head) softmax(norm G) + proj fold -> Mm[b][48][192] bf16 ----
__global__ __launch_bounds__(256) void k_attn_mm(
    const float* __restrict__ Gm, const float* __restrict__ sq, const float* __restrict__ temp,
    const float* __restrict__ pw, bf16* __restrict__ Mm) {
  __shared__ float A[48][48];
  __shared__ float nk[48];
  int tid = threadIdx.x;
  int bh = blockIdx.x; int b = bh >> 2, hd = bh & 3;
  if (tid >= 64 && tid < 112)
    nk[tid - 64] = fmaxf(sqrtf(sq[384 + bh * 48 + tid - 64]), 1e-12f);
  __syncthreads();
  if (tid < 48) {
    float tv = temp[hd];
    float rq = 1.f / fmaxf(sqrtf(sq[bh * 48 + tid]), 1e-12f);
    const float* grow = Gm + (size_t)bh * 2304 + tid * 48;
    float mx = -1e30f;
#pragma unroll
    for (int d = 0; d < 48; ++d) mx = fmaxf(mx, grow[d] * rq / nk[d] * tv);
    float sum = 0.f;
#pragma unroll
    for (int d = 0; d < 48; ++d) {
      float e = expf(grow[d] * rq / nk[d] * tv - mx);
      A[tid][d] = e; sum += e;
    }
    float inv = 1.f / sum;
#pragma unroll
    for (int d = 0; d < 48; ++d) A[tid][d] *= inv;
  }
  __syncthreads();
  for (int j = tid; j < 2304; j += 256) {
    int m = j / 48, d = j - m * 48;
    float a = 0.f;
#pragma unroll
    for (int c = 0; c < 48; ++c) a = fmaf(pw[m * 192 + hd * 48 + c], A[c][d], a);
    Mm[((size_t)b * 48 + m) * 192 + hd * 48 + d] = f2b(a * 0.0625f);
  }
}

// ------- K=192 GEMM: out = x + pb + Mm[b] @ v8[b]  (fp8 v, bf16 MFMA) -------------
__global__ __launch_bounds__(256) void k_av192(
    const unsigned char* __restrict__ vd8, const bf16* __restrict__ Mm,
    const float* __restrict__ pb, const float* __restrict__ x, float* __restrict__ outp) {
  __shared__ unsigned short Yl[96][130];
  __shared__ unsigned short Ml[48][200];
  int tid = threadIdx.x;
  int bt = blockIdx.x;
  int b = bt >> 9;
  int n0 = (bt & 511) * 128;
  int wv = tid >> 6, ln = tid & 63, lq = ln >> 4, li = ln & 15;
  const unsigned short* mb = (const unsigned short*)(Mm + (size_t)b * 48 * 192);
  for (int j = tid; j < 48 * 48; j += 256) {       // stage M (48 x 192)
    int m = j / 48, c4 = j - m * 48;
    *(ushort4*)&Ml[m][c4 * 4] = *(const ushort4*)(mb + m * 192 + c4 * 4);
  }
  const unsigned char* vb = vd8 + ((size_t)b * C2) * NPB + n0;
  f32x4 acc[3][2];
#pragma unroll
  for (int mt = 0; mt < 3; ++mt)
#pragma unroll
    for (int ns = 0; ns < 2; ++ns) acc[mt][ns] = (f32x4){0.f, 0.f, 0.f, 0.f};
#pragma unroll 1
  for (int s = 0; s < 2; ++s) {
    __syncthreads();
    for (int j = tid; j < 96 * 32; j += 256) {     // stage V half (96 x 128), decode
      int c = j >> 5, sub = j & 31;
      uchar4 u = *(const uchar4*)(vb + (size_t)(s * 96 + c) * NPB + sub * 4);
      *(ushort2*)&Yl[c][sub * 4]     = make_ushort2(f2us(fp82f(u.x)), f2us(fp82f(u.y)));
      *(ushort2*)&Yl[c][sub * 4 + 2] = make_ushort2(f2us(fp82f(u.z)), f2us(fp82f(u.w)));
    }
    __syncthreads();
#pragma unroll 1
    for (int ns = 0; ns < 2; ++ns) {
      int nn = wv * 32 + ns * 16 + li;
      short8 bfr[3];
#pragma unroll
      for (int ks = 0; ks < 3; ++ks)
#pragma unroll
        for (int j = 0; j < 8; ++j)
          bfr[ks][j] = (short)Yl[ks * 32 + lq * 8 + j][nn];
#pragma unroll
      for (int mt = 0; mt < 3; ++mt) {
        short8 a0 = *(const short8*)&Ml[mt * 16 + li][s * 96 + lq * 8];
        short8 a1 = *(const short8*)&Ml[mt * 16 + li][s * 96 + 32 + lq * 8];
        short8 a2 = *(const short8*)&Ml[mt * 16 + li][s * 96 + 64 + lq * 8];
        acc[mt][ns] = __builtin_amdgcn_mfma_f32_16x16x32_bf16(a0, bfr[0], acc[mt][ns], 0, 0, 0);
        acc[mt][ns] = __builtin_amdgcn_mfma_f32_16x16x32_bf16(a1, bfr[1], acc[mt][ns], 0, 0, 0);
        acc[mt][ns] = __builtin_amdgcn_mfma_f32_16x16x32_bf16(a2, bfr[2], acc[mt][ns], 0, 0, 0);
      }
    }
  }
#pragma unroll
  for (int ns = 0; ns < 2; ++ns) {
    int nn = wv * 32 + ns * 16 + li;
#pragma unroll
    for (int mt = 0; mt < 3; ++mt)
#pragma unroll
      for (int r = 0; r < 4; ++r) {
        int m = mt * 16 + lq * 4 + r;
        size_t idx = ((size_t)b * DIMC + m) * NPB + n0 + nn;
        outp[idx] = x[idx] + pb[m] + acc[mt][ns][r];
      }
  }
}

// ---------------- MFMA K=96 GEMM (pout), fp8(x16) input: out = addend+bias+W@g ----
__global__ __launch_bounds__(256) void k_ek96(
    const unsigned char* __restrict__ V, const float* __restrict__ W, int wrs,
    const float* __restrict__ bias, const float* __restrict__ addend, float* __restrict__ outp) {
  __shared__ unsigned short Yl[96][130];
  __shared__ unsigned short Wl[48][104];
  int tid = threadIdx.x;
  int bt = blockIdx.x;
  int b = bt >> 9;
  int n0 = (bt & 511) * 128;
  const unsigned char* vb = V + ((size_t)b * 96) * NPB + n0;
  for (int j = tid; j < 96 * 32; j += 256) {
    int c = j >> 5, sub = j & 31;
    uchar4 u = *(const uchar4*)(vb + (size_t)c * NPB + sub * 4);
    *(ushort2*)&Yl[c][sub * 4]     = make_ushort2(f2us(fp82f(u.x)), f2us(fp82f(u.y)));
    *(ushort2*)&Yl[c][sub * 4 + 2] = make_ushort2(f2us(fp82f(u.z)), f2us(fp82f(u.w)));
  }
  if (tid < 48) {
    const float* wr = W + (size_t)tid * wrs;
    unsigned short* wl = Wl[tid];
#pragma unroll
    for (int c = 0; c < 96; ++c) wl[c] = f2us(wr[c] * 0.0625f);   // cancel x16
  }
  __syncthreads();
  int wv = tid >> 6, ln = tid & 63, lq = ln >> 4, li = ln & 15;
  short8 afr[3][3];
#pragma unroll
  for (int mt = 0; mt < 3; ++mt)
#pragma unroll
    for (int ks = 0; ks < 3; ++ks)
      afr[mt][ks] = *(const short8*)&Wl[mt * 16 + li][ks * 32 + lq * 8];
#pragma unroll 1
  for (int ns = 0; ns < 2; ++ns) {
    int nn = wv * 32 + ns * 16 + li;
    short8 bfr[3];
#pragma unroll
    for (int ks = 0; ks < 3; ++ks)
#pragma unroll
      for (int j = 0; j < 8; ++j)
        bfr[ks][j] = (short)Yl[ks * 32 + lq * 8 + j][nn];
#pragma unroll
    for (int mt = 0; mt < 3; ++mt) {
      f32x4 acc = {0.f, 0.f, 0.f, 0.f};
      acc = __builtin_amdgcn_mfma_f32_16x16x32_bf16(afr[mt][0], bfr[0], acc, 0, 0, 0);
      acc = __builtin_amdgcn_mfma_f32_16x16x32_bf16(afr[mt][1], bfr[1], acc, 0, 0, 0);
      acc = __builtin_amdgcn_mfma_f32_16x16x32_bf16(afr[mt][2], bfr[2], acc, 0, 0, 0);
#pragma unroll
      for (int r = 0; r < 4; ++r) {
        int m = mt * 16 + lq * 4 + r;
        size_t idx = ((size_t)b * DIMC + m) * NPB + n0 + nn;
        outp[idx] = acc[r] + addend[idx] + bias[m];
      }
    }
  }
}

// ------- depthwise 3x3x3 + GELU gate; f32-LDS (1 ch/pass, stride 67) --------------
// grid (32, 96, 2): x = t-tile(8) x h-tile(4) [2t x 16h x 64w], y = ch pair.
__global__ __launch_bounds__(256) void k_dw_gelu(
    const unsigned char* __restrict__ z, const float* __restrict__ dwW,
    const float* __restrict__ dwB, unsigned char* __restrict__ g) {
  __shared__ float tile[4][18][67];      // odd stride -> 2-way staging banks (free)
  int tid = threadIdx.x;
  int t0 = (blockIdx.x >> 2) * 2, h0 = (blockIdx.x & 3) * 16;
  int c = blockIdx.y, b = blockIdx.z;
  int wp = tid & 31, hq = tid >> 5;
  float a[2][2][2][2];                   // [ch][t][i][wg]
#pragma unroll
  for (int ch = 0; ch < 2; ++ch)
#pragma unroll
    for (int t = 0; t < 2; ++t)
#pragma unroll
      for (int i = 0; i < 2; ++i) { a[ch][t][i][0] = 0.f; a[ch][t][i][1] = 0.f; }
#pragma unroll 1
  for (int ch = 0; ch < 2; ++ch) {
    const unsigned char* zp = z + ((size_t)b * C2 + c + ch * HIDC) * NPB;
    __syncthreads();
    for (int j = tid; j < 72 * 16; j += 256) {     // stage 4tt x 18hh x 64w
      int r = j >> 4, sub = j & 15;
      int tt = r / 18, hh = r - tt * 18;
      int gt = t0 + tt - 1, gh = h0 + hh - 1;
      float* dp = &tile[tt][hh][1 + sub * 4];
      if ((unsigned)gt < 16u && (unsigned)gh < 64u) {
        uchar4 u = *(const uchar4*)(zp + gt * 4096 + gh * 64 + sub * 4);
        dp[0] = fp82f(u.x); dp[1] = fp82f(u.y); dp[2] = fp82f(u.z); dp[3] = fp82f(u.w);
      } else { dp[0] = 0.f; dp[1] = 0.f; dp[2] = 0.f; dp[3] = 0.f; }
    }
    for (int j = tid; j < 144; j += 256) {
      int r = j >> 1, side = j & 1;
      int tt = r / 18, hh = r - tt * 18;
      tile[tt][hh][side ? 65 : 0] = 0.f;
    }
    __syncthreads();
    const float* wt = dwW + (size_t)(c + ch * HIDC) * 27;
#pragma unroll
    for (int wg = 0; wg < 2; ++wg) {
      int w0 = wp + wg * 32;
      float v[4][4][3];
#pragma unroll
      for (int tt = 0; tt < 4; ++tt)
#pragma unroll
        for (int rr = 0; rr < 4; ++rr)
#pragma unroll
          for (int dc = 0; dc < 3; ++dc)
            v[tt][rr][dc] = tile[tt][2 * hq + rr][w0 + dc];
#pragma unroll
      for (int dt = 0; dt < 3; ++dt)
#pragma unroll
        for (int dh = 0; dh < 3; ++dh)
#pragma unroll
          for (int dw = 0; dw < 3; ++dw) {
            float wv = wt[dt * 9 + dh * 3 + dw];
#pragma unroll
            for (int t = 0; t < 2; ++t)
#pragma unroll
              for (int i = 0; i < 2; ++i)
                a[ch][t][i][wg] = fmaf(wv, v[t + dt][i + dh][dw], a[ch][t][i][wg]);
          }
    }
  }
  float b1 = dwB[c], b2v = dwB[c + HIDC];
  size_t obase = ((size_t)b * HIDC + c) * NPB;
#pragma unroll
  for (int t = 0; t < 2; ++t)
#pragma unroll
    for (int i = 0; i < 2; ++i)
#pragma unroll
      for (int wg = 0; wg < 2; ++wg) {
        float x1v = a[0][t][i][wg] * 0.0625f + b1;
        float x2v = a[1][t][i][wg] * 0.0625f + b2v;
        float ge = 0.5f * x1v * (1.f + erff(x1v * 0.70710678118654752f));
        g[obase + (t0 + t) * 4096 + (h0 + 2 * hq + i) * 64 + wp + wg * 32] =
            f2fp8(16.f * ge * x2v);
      }
}

extern "C" void kernel_launch(void* const* d_in, const int* in_sizes, int n_in,
                              void* d_out, int out_size, void* d_ws, size_t ws_size,
                              hipStream_t stream) {
  (void)in_sizes; (void)n_in; (void)out_size; (void)ws_size;
  const float* x     = (const float*)d_in[0];
  const float* ln1w  = (const float*)d_in[1];
  const float* ln1b  = (const float*)d_in[2];
  const float* qkvw  = (const float*)d_in[3];
  const float* qkvb  = (const float*)d_in[4];
  const float* gdww  = (const float*)d_in[5];
  const float* gdwb  = (const float*)d_in[6];
  const float* temp  = (const float*)d_in[7];
  const float* projw = (const float*)d_in[8];
  const float* projb = (const float*)d_in[9];
  const float* ln2w  = (const float*)d_in[10];
  const float* ln2b  = (const float*)d_in[11];
  const float* pinw  = (const float*)d_in[12];
  const float* pinb  = (const float*)d_in[13];
  const float* dww   = (const float*)d_in[14];
  const float* dwb   = (const float*)d_in[15];
  const float* poutw = (const float*)d_in[16];
  const float* poutb = (const float*)d_in[17];
  float* out = (float*)d_out;

  // Workspace: y 12.6M | st288 37.7M | vd8 25.2M | Gm/sq/Mm tail -> 75.61M (proven)
  // qkd8 lives in d_out (exactly 25,165,824 B), dead before k_av192 writes out.
  char* ws = (char*)d_ws;
  bf16*  y     = (bf16*)(ws);                              // 12,582,912 B
  unsigned char* st288 = (unsigned char*)(ws + 12582912);  // 37,748,736 B [2][288][NPB]
  unsigned char* vd8   = (unsigned char*)(ws + 50331648);  // 25,165,824 B [2][192][NPB]
  float* Gm    = (float*)(ws + 75497472);                  //     73,728 B
  float* sq    = (float*)(ws + 75571200);                  //      3,072 B
  bf16*  Mm    = (bf16*)(ws + 75574272);                   //     36,864 B
  unsigned char* qkd8 = (unsigned char*)d_out;             // 25,165,824 B (scratch)
  // FFN phase (attention buffers dead):
  bf16*  y2    = (bf16*)(ws);                              // 12,582,912 B
  unsigned char* z8  = (unsigned char*)(ws + 12582912);    // 25,165,824 B
  unsigned char* gg8 = (unsigned char*)(ws + 37748736);    // 12,582,912 B

  hipMemsetAsync(Gm, 0, 73728 + 3072, stream);
  k_ln<<<dim3(512), dim3(256), 0, stream>>>(x, ln1w, ln1b, y);

  for (int hp = 0; hp < 2; ++hp) {
    // q,k,v pointwise for head pair (6 sections), fp8 out -> st288
    k_pconv_sec<<<dim3(6, 1024), dim3(256), 0, stream>>>(y, qkvw, qkvb, hp, st288, 288);
    // grouped dw-conv q+k (192 ch, 48 groups) -> qkd8 (in d_out) + sumsq
    k_gconv48<<<dim3(32, 48, 2), dim3(256), 0, stream>>>(
        st288, 0, gdww, gdwb, qkd8, hp, 0, sq);
    // Gram for both heads of the pair
    k_gram_mfma<<<dim3(64, 2, 2), dim3(256), 0, stream>>>(qkd8, hp, Gm);
    // grouped dw-conv v (96 ch, 24 groups) -> vd8 slots
    k_gconv48<<<dim3(32, 24, 2), dim3(256), 0, stream>>>(
        st288, 192, gdww, gdwb, vd8, hp, 1, nullptr);
  }
  k_attn_mm<<<dim3(8), dim3(256), 0, stream>>>(Gm, sq, temp, projw, Mm);
  k_av192<<<dim3(1024), dim3(256), 0, stream>>>(vd8, Mm, projb, x, out);

  k_ln<<<dim3(512), dim3(256), 0, stream>>>(out, ln2w, ln2b, y2);
  k_pconv_sec<<<dim3(4, 1024), dim3(256), 0, stream>>>(y2, pinw, pinb, -1, z8, 192);
  k_dw_gelu<<<dim3(32, 96, 2), dim3(256), 0, stream>>>(z8, dww, dwb, gg8);
  k_ek96<<<dim3(1024), dim3(256), 0, stream>>>(gg8, poutw, 96, poutb, out, out);
}